// Round 3
// baseline (1749.804 us; speedup 1.0000x reference)
//
#include <hip/hip_runtime.h>
#include <hip/hip_bf16.h>

// Problem dims (fixed)
#define N_LIG   10000
#define N_PROT  40000
#define NN      50000     // total nodes
#define EDGES   400000
#define BATCH   512
#define F_LIG   74
#define F_PROT  1280
#define HD      256       // H*D
#define HEADS   4
#define DIM     64

// Runtime-dtype load: f==1 -> float32 buffer, f==0 -> bf16 buffer.
__device__ inline float ldF(const void* p, size_t i, int f) {
    return f ? ((const float*)p)[i]
             : __bfloat162float(((const __hip_bfloat16*)p)[i]);
}

// ---------------- input dtype detector ----------------
// Interpret first n uint16s as bf16; f32 buffers have random low-half bit
// patterns -> exponent >= 0xC4 (|x| >= 2^69) occurs ~20% of the time.
// True bf16 ~N(0,1) data never does. flag := 1 if f32 detected.
__global__ void k_detect(const unsigned short* __restrict__ u, int n, int* __restrict__ flag) {
    int i = blockIdx.x * blockDim.x + threadIdx.x;
    if (i < n) {
        unsigned short e = (u[i] >> 7) & 0xFF;
        if (e >= 0xC4) atomicOr(flag, 1);
    }
}

// ---------------- CSR build ----------------

__global__ void k_hist(const int* __restrict__ dst, int* __restrict__ counts, int E) {
    int e = blockIdx.x * blockDim.x + threadIdx.x;
    if (e < E) atomicAdd(&counts[dst[e]], 1);
}

// inclusive scan per 1024-block + block sums
__global__ __launch_bounds__(1024) void k_scan1(const int* __restrict__ counts,
                                                int* __restrict__ incl,
                                                int* __restrict__ bsum, int N) {
    __shared__ int tmp[1024];
    int i = blockIdx.x * 1024 + threadIdx.x;
    int v = (i < N) ? counts[i] : 0;
    tmp[threadIdx.x] = v;
    __syncthreads();
    for (int off = 1; off < 1024; off <<= 1) {
        int add = (threadIdx.x >= (unsigned)off) ? tmp[threadIdx.x - off] : 0;
        __syncthreads();
        tmp[threadIdx.x] += add;
        __syncthreads();
    }
    if (i < N) incl[i] = tmp[threadIdx.x];
    if (threadIdx.x == 1023) bsum[blockIdx.x] = tmp[1023];
}

// serial exclusive scan of 49 block sums (tiny)
__global__ void k_scan2(int* __restrict__ bsum, int nb, int* __restrict__ row_ptr, int N, int E) {
    if (threadIdx.x == 0 && blockIdx.x == 0) {
        int run = 0;
        for (int i = 0; i < nb; ++i) { int v = bsum[i]; bsum[i] = run; run += v; }
        row_ptr[N] = E;
    }
}

__global__ __launch_bounds__(1024) void k_scan3(const int* __restrict__ incl,
                                                const int* __restrict__ counts,
                                                const int* __restrict__ bsum,
                                                int* __restrict__ row_ptr, int N) {
    int i = blockIdx.x * 1024 + threadIdx.x;
    if (i < N) row_ptr[i] = bsum[blockIdx.x] + incl[i] - counts[i];  // exclusive
}

__global__ void k_scatter(const int* __restrict__ src, const int* __restrict__ dst,
                          const int* __restrict__ row_ptr, int* __restrict__ cursor,
                          int* __restrict__ csr_src, int E) {
    int e = blockIdx.x * blockDim.x + threadIdx.x;
    if (e < E) {
        int d = dst[e];
        int pos = row_ptr[d] + atomicAdd(&cursor[d], 1);
        csr_src[pos] = src[e];
    }
}

// ---------------- Tiled GEMM: C[M,256] = A[M,K] * B[K,256], f32 accum ----------------
// A: input tensor (dtype by flag) if aIsInput, else f32 intermediate.
// B: input weight (dtype by flag). C: f32.
__global__ __launch_bounds__(256) void gemm64(const void* __restrict__ A,
                                              const void* __restrict__ B,
                                              float* __restrict__ C, int M, int K,
                                              const int* __restrict__ dflag, int aIsInput) {
    int f = *dflag;              // 1 = inputs are f32
    int af = aIsInput ? f : 1;   // intermediates always f32
    __shared__ float As[16][64 + 1];  // [k][m]
    __shared__ float Bs[16][64 + 1];  // [k][n]
    int bm = blockIdx.y * 64;
    int bn = blockIdx.x * 64;
    int tid = threadIdx.x;
    int tx = tid & 15, ty = tid >> 4;
    float acc[4][4] = {};
    for (int k0 = 0; k0 < K; k0 += 16) {
        {   // A tile: 64 rows x 16 k
            int m = tid >> 2;
            int kk = (tid & 3) * 4;
            int gm = bm + m;
            #pragma unroll
            for (int i = 0; i < 4; ++i) {
                int gk = k0 + kk + i;
                float v = 0.f;
                if (gm < M && gk < K) v = ldF(A, (size_t)gm * K + gk, af);
                As[kk + i][m] = v;
            }
        }
        {   // B tile: 16 k x 64 n
            int kk = tid >> 4;
            int nn = (tid & 15) * 4;
            int gk = k0 + kk;
            #pragma unroll
            for (int i = 0; i < 4; ++i) {
                float v = 0.f;
                if (gk < K) v = ldF(B, (size_t)gk * HD + bn + nn + i, f);
                Bs[kk][nn + i] = v;
            }
        }
        __syncthreads();
        #pragma unroll
        for (int k = 0; k < 16; ++k) {
            float a[4], b[4];
            #pragma unroll
            for (int i = 0; i < 4; ++i) a[i] = As[k][ty * 4 + i];
            #pragma unroll
            for (int j = 0; j < 4; ++j) b[j] = Bs[k][tx * 4 + j];
            #pragma unroll
            for (int i = 0; i < 4; ++i)
                #pragma unroll
                for (int j = 0; j < 4; ++j) acc[i][j] += a[i] * b[j];
        }
        __syncthreads();
    }
    #pragma unroll
    for (int i = 0; i < 4; ++i) {
        int gm = bm + ty * 4 + i;
        if (gm < M) {
            #pragma unroll
            for (int j = 0; j < 4; ++j)
                C[(size_t)gm * HD + bn + tx * 4 + j] = acc[i][j];
        }
    }
}

// ---------------- attention logits: att_s/att_d [N,4] ----------------
__global__ __launch_bounds__(256) void att_kernel(const float* __restrict__ hW,
                                                  const void* __restrict__ a_src,
                                                  const void* __restrict__ a_dst,
                                                  float* __restrict__ att_s,
                                                  float* __restrict__ att_d, int N,
                                                  const int* __restrict__ dflag) {
    int f = *dflag;
    int n = blockIdx.x;
    int d = threadIdx.x;          // 0..255; head = d>>6, lane-in-head = d&63
    int lane = d & 63, head = d >> 6;
    float h = hW[(size_t)n * HD + d];
    float s = h * ldF(a_src, d, f);
    float t = h * ldF(a_dst, d, f);
    for (int off = 32; off > 0; off >>= 1) {
        s += __shfl_down(s, off, 64);
        t += __shfl_down(t, off, 64);
    }
    if (lane == 0) {
        att_s[n * HEADS + head] = s;
        att_d[n * HEADS + head] = t;
    }
}

// ---------------- GAT edge-softmax + aggregation (per destination node) ----------------
// block = 256 threads = 4 waves; wave w handles head w; lane = output dim within head.
__global__ __launch_bounds__(256) void gat_agg(const float* __restrict__ hW,
                                               const float* __restrict__ att_s,
                                               const float* __restrict__ att_d,
                                               const int* __restrict__ row_ptr,
                                               const int* __restrict__ csr_src,
                                               float* __restrict__ out, int N) {
    int n = blockIdx.x;
    int t = threadIdx.x;
    int lane = t & 63, head = t >> 6;
    int r0 = row_ptr[n], r1 = row_ptr[n + 1];
    int deg = r1 - r0;
    float ad = att_d[n * HEADS + head];

    // pass 1: segment max of leaky_relu(att_s[src]+att_d[n])
    float m = -INFINITY;
    for (int base = 0; base < deg; base += 64) {
        int i = base + lane;
        float e = -INFINITY;
        if (i < deg) {
            int s = csr_src[r0 + i];
            float x = att_s[s * HEADS + head] + ad;
            e = (x >= 0.f) ? x : 0.2f * x;
        }
        for (int off = 32; off > 0; off >>= 1) e = fmaxf(e, __shfl_xor(e, off, 64));
        m = fmaxf(m, e);
    }

    // pass 2: weights + weighted aggregation
    float acc = 0.f, wsum = 0.f;
    for (int base = 0; base < deg; base += 64) {
        int i = base + lane;
        float w = 0.f; int s = 0;
        if (i < deg) {
            s = csr_src[r0 + i];
            float x = att_s[s * HEADS + head] + ad;
            x = (x >= 0.f) ? x : 0.2f * x;
            w = expf(x - m);
        }
        wsum += w;
        int cnt = min(64, deg - base);
        for (int j = 0; j < cnt; ++j) {
            float wj = __shfl(w, j, 64);
            int   sj = __shfl(s, j, 64);
            acc += wj * hW[(size_t)sj * HD + head * DIM + lane];
        }
    }
    for (int off = 32; off > 0; off >>= 1) wsum += __shfl_xor(wsum, off, 64);
    float v = acc / (wsum + 1e-9f);
    out[(size_t)n * HD + t] = (v > 0.f) ? v : expm1f(v);  // ELU
}

// ---------------- mean pool per graph + final linear (f32 output!) ----------------
__global__ __launch_bounds__(256) void pool_out(const float* __restrict__ h,
                                                const int* __restrict__ gid,
                                                const void* __restrict__ W_out,
                                                const void* __restrict__ b_out,
                                                const void* __restrict__ scores,
                                                float* __restrict__ out, int N,
                                                const int* __restrict__ dflag) {
    int f = *dflag;
    int b = blockIdx.x;
    int j = threadIdx.x;
    // graph_ids sorted: binary search [lo,hi) for graph b
    int l = 0, r = N;
    while (l < r) { int mid = (l + r) >> 1; if (gid[mid] < b) l = mid + 1; else r = mid; }
    int lo = l;
    r = N;
    while (l < r) { int mid = (l + r) >> 1; if (gid[mid] < b + 1) l = mid + 1; else r = mid; }
    int hi = l;

    float sum = 0.f;
    for (int n = lo; n < hi; ++n) sum += h[(size_t)n * HD + j];
    int cnt = hi - lo;
    float pooled = sum / fmaxf((float)cnt, 1.f);
    float val = pooled * ldF(W_out, j, f);

    __shared__ float red[256];
    red[j] = val;
    __syncthreads();
    for (int s = 128; s > 0; s >>= 1) {
        if (j < s) red[j] += red[j + s];
        __syncthreads();
    }
    if (j == 0) {
        float rsum = red[0]
                   + ldF(scores, b, f) * ldF(W_out, HD, f)
                   + ldF(b_out, 0, f);
        out[b] = rsum;
    }
}

// ---------------- host ----------------

static inline size_t al256(size_t x) { return (x + 255) & ~(size_t)255; }

extern "C" void kernel_launch(void* const* d_in, const int* in_sizes, int n_in,
                              void* d_out, int out_size, void* d_ws, size_t ws_size,
                              hipStream_t stream) {
    const void* ligand_x  = d_in[0];
    const void* protein_x = d_in[1];
    const void* W_lig     = d_in[2];
    const void* W_prot    = d_in[3];
    const void* W1        = d_in[4];
    const void* a1_src    = d_in[5];
    const void* a1_dst    = d_in[6];
    const void* W2        = d_in[7];
    const void* a2_src    = d_in[8];
    const void* a2_dst    = d_in[9];
    const void* W_out     = d_in[10];
    const void* b_out     = d_in[11];
    const int*  edge_src  = (const int*)d_in[12];
    const int*  edge_dst  = (const int*)d_in[13];
    const int*  graph_ids = (const int*)d_in[14];
    const void* scores    = d_in[15];
    float* out = (float*)d_out;

    // workspace layout (~107 MB)
    char* w = (char*)d_ws;
    int* dflag   = (int*)w;             w += 256;
    float* xbuf = (float*)w;            w += al256((size_t)NN * HD * 4);
    float* hbuf = (float*)w;            w += al256((size_t)NN * HD * 4);
    float* atts = (float*)w;            w += al256((size_t)NN * HEADS * 4);
    float* attd = (float*)w;            w += al256((size_t)NN * HEADS * 4);
    int* counts  = (int*)w;             w += al256((size_t)NN * 4);
    int* incl    = (int*)w;             w += al256((size_t)NN * 4);
    int* bsum    = (int*)w;             w += al256(64 * 4);
    int* row_ptr = (int*)w;             w += al256((size_t)(NN + 1) * 4);
    int* cursor  = (int*)w;             w += al256((size_t)NN * 4);
    int* csr_src = (int*)w;             w += al256((size_t)EDGES * 4);

    const int NB_SCAN = (NN + 1023) / 1024;  // 49

    // --- dtype detect + zero init (ws is poisoned 0xAA before every launch) ---
    hipMemsetAsync(dflag, 0, 4, stream);
    hipMemsetAsync(counts, 0, (size_t)NN * 4, stream);
    hipMemsetAsync(cursor, 0, (size_t)NN * 4, stream);
    k_detect<<<256, 256, 0, stream>>>((const unsigned short*)protein_x, 65536, dflag);

    // --- CSR by destination ---
    k_hist<<<(EDGES + 255) / 256, 256, 0, stream>>>(edge_dst, counts, EDGES);
    k_scan1<<<NB_SCAN, 1024, 0, stream>>>(counts, incl, bsum, NN);
    k_scan2<<<1, 1, 0, stream>>>(bsum, NB_SCAN, row_ptr, NN, EDGES);
    k_scan3<<<NB_SCAN, 1024, 0, stream>>>(incl, counts, bsum, row_ptr, NN);
    k_scatter<<<(EDGES + 255) / 256, 256, 0, stream>>>(edge_src, edge_dst, row_ptr,
                                                       cursor, csr_src, EDGES);

    // --- input projections -> xbuf [NN,256] ---
    gemm64<<<dim3(4, (N_LIG + 63) / 64), 256, 0, stream>>>(
        ligand_x, W_lig, xbuf, N_LIG, F_LIG, dflag, 1);
    gemm64<<<dim3(4, (N_PROT + 63) / 64), 256, 0, stream>>>(
        protein_x, W_prot, xbuf + (size_t)N_LIG * HD, N_PROT, F_PROT, dflag, 1);

    // --- GAT layer 1: xbuf -> (hbuf) -> xbuf ---
    gemm64<<<dim3(4, (NN + 63) / 64), 256, 0, stream>>>(xbuf, W1, hbuf, NN, HD, dflag, 0);
    att_kernel<<<NN, 256, 0, stream>>>(hbuf, a1_src, a1_dst, atts, attd, NN, dflag);
    gat_agg<<<NN, 256, 0, stream>>>(hbuf, atts, attd, row_ptr, csr_src, xbuf, NN);

    // --- GAT layer 2: xbuf -> (hbuf) -> xbuf ---
    gemm64<<<dim3(4, (NN + 63) / 64), 256, 0, stream>>>(xbuf, W2, hbuf, NN, HD, dflag, 0);
    att_kernel<<<NN, 256, 0, stream>>>(hbuf, a2_src, a2_dst, atts, attd, NN, dflag);
    gat_agg<<<NN, 256, 0, stream>>>(hbuf, atts, attd, row_ptr, csr_src, xbuf, NN);

    // --- pool + final linear ---
    pool_out<<<BATCH, 256, 0, stream>>>(xbuf, graph_ids, W_out, b_out, scores, out, NN, dflag);
}

// Round 4
// 903.208 us; speedup vs baseline: 1.9373x; 1.9373x over previous
//
#include <hip/hip_runtime.h>
#include <hip/hip_bf16.h>

// Problem dims (fixed)
#define N_LIG   10000
#define N_PROT  40000
#define NN      50000     // total nodes
#define EDGES   400000
#define BATCH   512
#define F_LIG   74
#define F_PROT  1280
#define HD      256       // H*D
#define HEADS   4
#define DIM     64

typedef __bf16 bf16x8 __attribute__((ext_vector_type(8)));
typedef __bf16 bf16x4 __attribute__((ext_vector_type(4)));
typedef float  f32x4  __attribute__((ext_vector_type(4)));

// ---------------- CSR build ----------------

__global__ void k_hist(const int* __restrict__ dst, int* __restrict__ counts, int E) {
    int e = blockIdx.x * blockDim.x + threadIdx.x;
    if (e < E) atomicAdd(&counts[dst[e]], 1);
}

__global__ __launch_bounds__(1024) void k_scan1(const int* __restrict__ counts,
                                                int* __restrict__ incl,
                                                int* __restrict__ bsum, int N) {
    __shared__ int tmp[1024];
    int i = blockIdx.x * 1024 + threadIdx.x;
    int v = (i < N) ? counts[i] : 0;
    tmp[threadIdx.x] = v;
    __syncthreads();
    for (int off = 1; off < 1024; off <<= 1) {
        int add = (threadIdx.x >= (unsigned)off) ? tmp[threadIdx.x - off] : 0;
        __syncthreads();
        tmp[threadIdx.x] += add;
        __syncthreads();
    }
    if (i < N) incl[i] = tmp[threadIdx.x];
    if (threadIdx.x == 1023) bsum[blockIdx.x] = tmp[1023];
}

__global__ void k_scan2(int* __restrict__ bsum, int nb, int* __restrict__ row_ptr, int N, int E) {
    if (threadIdx.x == 0 && blockIdx.x == 0) {
        int run = 0;
        for (int i = 0; i < nb; ++i) { int v = bsum[i]; bsum[i] = run; run += v; }
        row_ptr[N] = E;
    }
}

__global__ __launch_bounds__(1024) void k_scan3(const int* __restrict__ incl,
                                                const int* __restrict__ counts,
                                                const int* __restrict__ bsum,
                                                int* __restrict__ row_ptr, int N) {
    int i = blockIdx.x * 1024 + threadIdx.x;
    if (i < N) row_ptr[i] = bsum[blockIdx.x] + incl[i] - counts[i];  // exclusive
}

__global__ void k_scatter(const int* __restrict__ src, const int* __restrict__ dst,
                          const int* __restrict__ row_ptr, int* __restrict__ cursor,
                          int* __restrict__ csr_src, int E) {
    int e = blockIdx.x * blockDim.x + threadIdx.x;
    if (e < E) {
        int d = dst[e];
        int pos = row_ptr[d] + atomicAdd(&cursor[d], 1);
        csr_src[pos] = src[e];
    }
}

// ---------------- weight transpose+convert: W f32 [K,256] -> Bt bf16 [256][Kp] ----------------
__global__ __launch_bounds__(256) void k_wcvt(const float* __restrict__ W,
                                              __bf16* __restrict__ Bt, int K, int Kp) {
    int n = blockIdx.x;   // 0..255
    for (int k = threadIdx.x; k < Kp; k += blockDim.x)
        Bt[(size_t)n * Kp + k] = (k < K) ? (__bf16)W[(size_t)k * HD + n] : (__bf16)0.f;
}

// ---------------- MFMA GEMM: C[M,256] = A[M,K](f32) * B[K,256] ----------------
// Bt: bf16 [256][Kp], k-major, zero-padded (weights are bf16-exact).
// SPLIT=0: A values are bf16-exact (raw inputs) -> single mfma.
// SPLIT=1: A is f32 intermediate -> hi/lo split, 2 mfma per k-step (f32-accurate).
// Tile: 128x128 per block, 4 waves in 2x2, 16x16x32 mfma, 4x4 acc frags per wave.
template <int SPLIT>
__global__ __launch_bounds__(256) void mfma_gemm(const float* __restrict__ A,
                                                 const __bf16* __restrict__ Bt,
                                                 float* __restrict__ C,
                                                 int M, int K, int Kp) {
    __shared__ __bf16 sA[128 * 40];    // [row][k], k padded 32->40 (bank-conflict pad)
    __shared__ __bf16 sAlo[128 * 40];
    __shared__ __bf16 sB[128 * 40];    // [col n][k]

    int tid  = threadIdx.x;
    int bm   = blockIdx.y * 128;
    int bn   = blockIdx.x * 128;
    int lane = tid & 63, wave = tid >> 6;
    int wr   = wave >> 1, wc = wave & 1;    // wave's 64x64 quadrant
    int l15  = lane & 15, quad = lane >> 4;

    f32x4 acc[4][4];
    #pragma unroll
    for (int i = 0; i < 4; ++i)
        #pragma unroll
        for (int j = 0; j < 4; ++j)
            acc[i][j] = (f32x4){0.f, 0.f, 0.f, 0.f};

    const bool k4 = (K & 3) == 0;

    for (int k0 = 0; k0 < K; k0 += 32) {
        __syncthreads();
        bool fullk = k4 && (k0 + 32 <= K);
        // ---- stage A: 128 rows x 32 k (f32 -> bf16 hi[/lo]) ----
        #pragma unroll
        for (int it = 0; it < 4; ++it) {
            int fl  = tid + it * 256;        // 0..1023
            int row = fl >> 3;               // 0..127
            int kq  = fl & 7;                // float4 slot within 32-k row
            int gm  = bm + row;
            float v[4];
            if (gm < M && fullk) {
                f32x4 t = *(const f32x4*)&A[(size_t)gm * K + k0 + kq * 4];
                v[0] = t[0]; v[1] = t[1]; v[2] = t[2]; v[3] = t[3];
            } else {
                #pragma unroll
                for (int j = 0; j < 4; ++j) {
                    int gk = k0 + kq * 4 + j;
                    v[j] = (gm < M && gk < K) ? A[(size_t)gm * K + gk] : 0.f;
                }
            }
            bf16x4 hi, lo;
            #pragma unroll
            for (int j = 0; j < 4; ++j) {
                hi[j] = (__bf16)v[j];
                if (SPLIT) lo[j] = (__bf16)(v[j] - (float)hi[j]);
            }
            *(bf16x4*)&sA[row * 40 + kq * 4] = hi;
            if (SPLIT) *(bf16x4*)&sAlo[row * 40 + kq * 4] = lo;
        }
        // ---- stage B: 128 cols x 32 k (bf16, contiguous 16B loads) ----
        #pragma unroll
        for (int it = 0; it < 2; ++it) {
            int fl  = tid + it * 256;        // 0..511
            int n   = fl >> 2;               // 0..127
            int seg = fl & 3;                // 8-bf16 segment
            bf16x8 t = *(const bf16x8*)&Bt[(size_t)(bn + n) * Kp + k0 + seg * 8];
            *(bf16x8*)&sB[n * 40 + seg * 8] = t;
        }
        __syncthreads();
        // ---- fragments + mfma ----
        bf16x8 af[4], bfr[4], al[4];
        #pragma unroll
        for (int i = 0; i < 4; ++i)
            af[i] = *(bf16x8*)&sA[(wr * 64 + i * 16 + l15) * 40 + quad * 8];
        if (SPLIT) {
            #pragma unroll
            for (int i = 0; i < 4; ++i)
                al[i] = *(bf16x8*)&sAlo[(wr * 64 + i * 16 + l15) * 40 + quad * 8];
        }
        #pragma unroll
        for (int j = 0; j < 4; ++j)
            bfr[j] = *(bf16x8*)&sB[(wc * 64 + j * 16 + l15) * 40 + quad * 8];
        #pragma unroll
        for (int i = 0; i < 4; ++i)
            #pragma unroll
            for (int j = 0; j < 4; ++j) {
                acc[i][j] = __builtin_amdgcn_mfma_f32_16x16x32_bf16(af[i], bfr[j], acc[i][j], 0, 0, 0);
                if (SPLIT)
                    acc[i][j] = __builtin_amdgcn_mfma_f32_16x16x32_bf16(al[i], bfr[j], acc[i][j], 0, 0, 0);
            }
    }
    // ---- epilogue: C/D layout col=lane&15, row=quad*4+reg ----
    #pragma unroll
    for (int i = 0; i < 4; ++i) {
        #pragma unroll
        for (int r = 0; r < 4; ++r) {
            int m = bm + wr * 64 + i * 16 + quad * 4 + r;
            if (m < M) {
                #pragma unroll
                for (int j = 0; j < 4; ++j) {
                    int n = bn + wc * 64 + j * 16 + l15;
                    C[(size_t)m * HD + n] = acc[i][j][r];
                }
            }
        }
    }
}

// ---------------- attention logits: att_s/att_d [N,4] ----------------
__global__ __launch_bounds__(256) void att_kernel(const float* __restrict__ hW,
                                                  const float* __restrict__ a_src,
                                                  const float* __restrict__ a_dst,
                                                  float* __restrict__ att_s,
                                                  float* __restrict__ att_d, int N) {
    int n = blockIdx.x;
    int d = threadIdx.x;          // head = d>>6, lane-in-head = d&63
    int lane = d & 63, head = d >> 6;
    float h = hW[(size_t)n * HD + d];
    float s = h * a_src[d];
    float t = h * a_dst[d];
    for (int off = 32; off > 0; off >>= 1) {
        s += __shfl_down(s, off, 64);
        t += __shfl_down(t, off, 64);
    }
    if (lane == 0) {
        att_s[n * HEADS + head] = s;
        att_d[n * HEADS + head] = t;
    }
}

// ---------------- GAT edge-softmax + aggregation (per destination node) ----------------
__global__ __launch_bounds__(256) void gat_agg(const float* __restrict__ hW,
                                               const float* __restrict__ att_s,
                                               const float* __restrict__ att_d,
                                               const int* __restrict__ row_ptr,
                                               const int* __restrict__ csr_src,
                                               float* __restrict__ out, int N) {
    int n = blockIdx.x;
    int t = threadIdx.x;
    int lane = t & 63, head = t >> 6;
    int r0 = row_ptr[n], r1 = row_ptr[n + 1];
    int deg = r1 - r0;
    float ad = att_d[n * HEADS + head];

    // pass 1: segment max of leaky_relu(att_s[src]+att_d[n])
    float m = -INFINITY;
    for (int base = 0; base < deg; base += 64) {
        int i = base + lane;
        float e = -INFINITY;
        if (i < deg) {
            int s = csr_src[r0 + i];
            float x = att_s[s * HEADS + head] + ad;
            e = (x >= 0.f) ? x : 0.2f * x;
        }
        for (int off = 32; off > 0; off >>= 1) e = fmaxf(e, __shfl_xor(e, off, 64));
        m = fmaxf(m, e);
    }

    // pass 2: weights + weighted aggregation
    float acc = 0.f, wsum = 0.f;
    for (int base = 0; base < deg; base += 64) {
        int i = base + lane;
        float w = 0.f; int s = 0;
        if (i < deg) {
            s = csr_src[r0 + i];
            float x = att_s[s * HEADS + head] + ad;
            x = (x >= 0.f) ? x : 0.2f * x;
            w = expf(x - m);
        }
        wsum += w;
        int cnt = min(64, deg - base);
        for (int j = 0; j < cnt; ++j) {
            float wj = __shfl(w, j, 64);
            int   sj = __shfl(s, j, 64);
            acc += wj * hW[(size_t)sj * HD + head * DIM + lane];
        }
    }
    for (int off = 32; off > 0; off >>= 1) wsum += __shfl_xor(wsum, off, 64);
    float v = acc / (wsum + 1e-9f);
    out[(size_t)n * HD + t] = (v > 0.f) ? v : expm1f(v);  // ELU
}

// ---------------- mean pool per graph + final linear (f32 output) ----------------
__global__ __launch_bounds__(256) void pool_out(const float* __restrict__ h,
                                                const int* __restrict__ gid,
                                                const float* __restrict__ W_out,
                                                const float* __restrict__ b_out,
                                                const float* __restrict__ scores,
                                                float* __restrict__ out, int N) {
    int b = blockIdx.x;
    int j = threadIdx.x;
    int l = 0, r = N;
    while (l < r) { int mid = (l + r) >> 1; if (gid[mid] < b) l = mid + 1; else r = mid; }
    int lo = l;
    r = N;
    while (l < r) { int mid = (l + r) >> 1; if (gid[mid] < b + 1) l = mid + 1; else r = mid; }
    int hi = l;

    float sum = 0.f;
    for (int n = lo; n < hi; ++n) sum += h[(size_t)n * HD + j];
    int cnt = hi - lo;
    float pooled = sum / fmaxf((float)cnt, 1.f);
    float val = pooled * W_out[j];

    __shared__ float red[256];
    red[j] = val;
    __syncthreads();
    for (int s = 128; s > 0; s >>= 1) {
        if (j < s) red[j] += red[j + s];
        __syncthreads();
    }
    if (j == 0) {
        out[b] = red[0] + scores[b] * W_out[HD] + b_out[0];
    }
}

// ---------------- host ----------------

static inline size_t al256(size_t x) { return (x + 255) & ~(size_t)255; }

#define KP_LIG  96
#define KP_PROT 1280
#define KP_HID  256

extern "C" void kernel_launch(void* const* d_in, const int* in_sizes, int n_in,
                              void* d_out, int out_size, void* d_ws, size_t ws_size,
                              hipStream_t stream) {
    const float* ligand_x  = (const float*)d_in[0];
    const float* protein_x = (const float*)d_in[1];
    const float* W_lig     = (const float*)d_in[2];
    const float* W_prot    = (const float*)d_in[3];
    const float* W1        = (const float*)d_in[4];
    const float* a1_src    = (const float*)d_in[5];
    const float* a1_dst    = (const float*)d_in[6];
    const float* W2        = (const float*)d_in[7];
    const float* a2_src    = (const float*)d_in[8];
    const float* a2_dst    = (const float*)d_in[9];
    const float* W_out     = (const float*)d_in[10];
    const float* b_out     = (const float*)d_in[11];
    const int*   edge_src  = (const int*)d_in[12];
    const int*   edge_dst  = (const int*)d_in[13];
    const int*   graph_ids = (const int*)d_in[14];
    const float* scores    = (const float*)d_in[15];
    float* out = (float*)d_out;

    // workspace layout
    char* w = (char*)d_ws;
    float* xbuf = (float*)w;            w += al256((size_t)NN * HD * 4);
    float* hbuf = (float*)w;            w += al256((size_t)NN * HD * 4);
    float* atts = (float*)w;            w += al256((size_t)NN * HEADS * 4);
    float* attd = (float*)w;            w += al256((size_t)NN * HEADS * 4);
    int* counts  = (int*)w;             w += al256((size_t)NN * 4);
    int* incl    = (int*)w;             w += al256((size_t)NN * 4);
    int* bsum    = (int*)w;             w += al256(64 * 4);
    int* row_ptr = (int*)w;             w += al256((size_t)(NN + 1) * 4);
    int* cursor  = (int*)w;             w += al256((size_t)NN * 4);
    int* csr_src = (int*)w;             w += al256((size_t)EDGES * 4);
    __bf16* Bt_lig  = (__bf16*)w;       w += al256((size_t)HD * KP_LIG * 2);
    __bf16* Bt_prot = (__bf16*)w;       w += al256((size_t)HD * KP_PROT * 2);
    __bf16* Bt_W1   = (__bf16*)w;       w += al256((size_t)HD * KP_HID * 2);
    __bf16* Bt_W2   = (__bf16*)w;       w += al256((size_t)HD * KP_HID * 2);

    const int NB_SCAN = (NN + 1023) / 1024;  // 49

    hipMemsetAsync(counts, 0, (size_t)NN * 4, stream);
    hipMemsetAsync(cursor, 0, (size_t)NN * 4, stream);

    // --- weight convert/transpose to bf16 (exact: inputs are bf16-rounded) ---
    k_wcvt<<<HD, 256, 0, stream>>>(W_lig,  Bt_lig,  F_LIG,  KP_LIG);
    k_wcvt<<<HD, 256, 0, stream>>>(W_prot, Bt_prot, F_PROT, KP_PROT);
    k_wcvt<<<HD, 256, 0, stream>>>(W1,     Bt_W1,   HD,     KP_HID);
    k_wcvt<<<HD, 256, 0, stream>>>(W2,     Bt_W2,   HD,     KP_HID);

    // --- CSR by destination ---
    k_hist<<<(EDGES + 255) / 256, 256, 0, stream>>>(edge_dst, counts, EDGES);
    k_scan1<<<NB_SCAN, 1024, 0, stream>>>(counts, incl, bsum, NN);
    k_scan2<<<1, 1, 0, stream>>>(bsum, NB_SCAN, row_ptr, NN, EDGES);
    k_scan3<<<NB_SCAN, 1024, 0, stream>>>(incl, counts, bsum, row_ptr, NN);
    k_scatter<<<(EDGES + 255) / 256, 256, 0, stream>>>(edge_src, edge_dst, row_ptr,
                                                       cursor, csr_src, EDGES);

    // --- input projections -> xbuf [NN,256] (A is bf16-exact: SPLIT=0) ---
    mfma_gemm<0><<<dim3(2, (N_LIG + 127) / 128), 256, 0, stream>>>(
        ligand_x, Bt_lig, xbuf, N_LIG, F_LIG, KP_LIG);
    mfma_gemm<0><<<dim3(2, (N_PROT + 127) / 128), 256, 0, stream>>>(
        protein_x, Bt_prot, xbuf + (size_t)N_LIG * HD, N_PROT, F_PROT, KP_PROT);

    // --- GAT layer 1 ---
    mfma_gemm<1><<<dim3(2, (NN + 127) / 128), 256, 0, stream>>>(
        xbuf, Bt_W1, hbuf, NN, HD, KP_HID);
    att_kernel<<<NN, 256, 0, stream>>>(hbuf, a1_src, a1_dst, atts, attd, NN);
    gat_agg<<<NN, 256, 0, stream>>>(hbuf, atts, attd, row_ptr, csr_src, xbuf, NN);

    // --- GAT layer 2 ---
    mfma_gemm<1><<<dim3(2, (NN + 127) / 128), 256, 0, stream>>>(
        xbuf, Bt_W2, hbuf, NN, HD, KP_HID);
    att_kernel<<<NN, 256, 0, stream>>>(hbuf, a2_src, a2_dst, atts, attd, NN);
    gat_agg<<<NN, 256, 0, stream>>>(hbuf, atts, attd, row_ptr, csr_src, xbuf, NN);

    // --- pool + final linear ---
    pool_out<<<BATCH, 256, 0, stream>>>(xbuf, graph_ids, W_out, b_out, scores, out, NN);
}

// Round 6
// 827.992 us; speedup vs baseline: 2.1133x; 1.0908x over previous
//
#include <hip/hip_runtime.h>
#include <hip/hip_bf16.h>

// Problem dims (fixed)
#define N_LIG   10000
#define N_PROT  40000
#define NN      50000     // total nodes
#define EDGES   400000
#define BATCH   512
#define F_LIG   74
#define F_PROT  1280
#define HD      256       // H*D
#define HEADS   4
#define DIM     64

typedef __bf16 bf16x8 __attribute__((ext_vector_type(8)));
typedef __bf16 bf16x4 __attribute__((ext_vector_type(4)));
typedef float  f32x4  __attribute__((ext_vector_type(4)));

// ---------------- CSR build ----------------

__global__ void k_hist(const int* __restrict__ dst, int* __restrict__ counts, int E) {
    int e = blockIdx.x * blockDim.x + threadIdx.x;
    if (e < E) atomicAdd(&counts[dst[e]], 1);
}

__global__ __launch_bounds__(1024) void k_scan1(const int* __restrict__ counts,
                                                int* __restrict__ incl,
                                                int* __restrict__ bsum, int N) {
    __shared__ int tmp[1024];
    int i = blockIdx.x * 1024 + threadIdx.x;
    int v = (i < N) ? counts[i] : 0;
    tmp[threadIdx.x] = v;
    __syncthreads();
    for (int off = 1; off < 1024; off <<= 1) {
        int add = (threadIdx.x >= (unsigned)off) ? tmp[threadIdx.x - off] : 0;
        __syncthreads();
        tmp[threadIdx.x] += add;
        __syncthreads();
    }
    if (i < N) incl[i] = tmp[threadIdx.x];
    if (threadIdx.x == 1023) bsum[blockIdx.x] = tmp[1023];
}

__global__ void k_scan2(int* __restrict__ bsum, int nb, int* __restrict__ row_ptr, int N, int E) {
    if (threadIdx.x == 0 && blockIdx.x == 0) {
        int run = 0;
        for (int i = 0; i < nb; ++i) { int v = bsum[i]; bsum[i] = run; run += v; }
        row_ptr[N] = E;
    }
}

__global__ __launch_bounds__(1024) void k_scan3(const int* __restrict__ incl,
                                                const int* __restrict__ counts,
                                                const int* __restrict__ bsum,
                                                int* __restrict__ row_ptr, int N) {
    int i = blockIdx.x * 1024 + threadIdx.x;
    if (i < N) row_ptr[i] = bsum[blockIdx.x] + incl[i] - counts[i];  // exclusive
}

__global__ void k_scatter(const int* __restrict__ src, const int* __restrict__ dst,
                          const int* __restrict__ row_ptr, int* __restrict__ cursor,
                          int* __restrict__ csr_src, int E) {
    int e = blockIdx.x * blockDim.x + threadIdx.x;
    if (e < E) {
        int d = dst[e];
        int pos = row_ptr[d] + atomicAdd(&cursor[d], 1);
        csr_src[pos] = src[e];
    }
}

// ---------------- weight transpose+convert: W f32 [K,256] -> Bt bf16 [256][Kp] ----------------
__global__ __launch_bounds__(256) void k_wcvt(const float* __restrict__ W,
                                              __bf16* __restrict__ Bt, int K, int Kp) {
    int n = blockIdx.x;   // 0..255
    for (int k = threadIdx.x; k < Kp; k += blockDim.x)
        Bt[(size_t)n * Kp + k] = (k < K) ? (__bf16)W[(size_t)k * HD + n] : (__bf16)0.f;
}

// ---------------- MFMA GEMM, double-buffered ----------------
// C[M,256] = A[M,K](f32) * B; Bt bf16 [256][Kp] k-major zero-padded.
// SPLIT=0: A bf16-exact (raw inputs). SPLIT=1: hi/lo split (f32-accurate).
// 128x128 tile, 4 waves 2x2, 16x16x32 mfma, 4x4 frags/wave.
// Dbuf: next tile's global loads issued BEFORE barrier (VGPR-dst, no LDS drain),
// convert+ds_write into alternate buffer after MFMAs.
#define PAD 40
template <int SPLIT>
__global__ __launch_bounds__(256, SPLIT ? 2 : 3) void mfma_gemm(const float* __restrict__ A,
                                                 const __bf16* __restrict__ Bt,
                                                 float* __restrict__ C,
                                                 int M, int K, int Kp) {
    __shared__ __bf16 sA[2][128 * PAD];
    __shared__ __bf16 sAlo[SPLIT ? 2 : 1][128 * PAD];  // dead (DCE'd) when SPLIT=0
    __shared__ __bf16 sB[2][128 * PAD];

    int tid  = threadIdx.x;
    int bm   = blockIdx.y * 128;
    int bn   = blockIdx.x * 128;
    int lane = tid & 63, wave = tid >> 6;
    int wr   = wave >> 1, wc = wave & 1;
    int l15  = lane & 15, quad = lane >> 4;

    f32x4 acc[4][4];
    #pragma unroll
    for (int i = 0; i < 4; ++i)
        #pragma unroll
        for (int j = 0; j < 4; ++j)
            acc[i][j] = (f32x4){0.f, 0.f, 0.f, 0.f};

    const bool k4 = (K & 3) == 0;
    float  va[4][4];
    bf16x8 vb[2];

    auto loadTile = [&](int k0) {
        bool fullk = k4 && (k0 + 32 <= K);
        #pragma unroll
        for (int it = 0; it < 4; ++it) {
            int fl = tid + it * 256, row = fl >> 3, kq = fl & 7;
            int gm = bm + row;
            if (gm < M && fullk) {
                f32x4 t = *(const f32x4*)&A[(size_t)gm * K + k0 + kq * 4];
                va[it][0] = t[0]; va[it][1] = t[1]; va[it][2] = t[2]; va[it][3] = t[3];
            } else {
                #pragma unroll
                for (int j = 0; j < 4; ++j) {
                    int gk = k0 + kq * 4 + j;
                    va[it][j] = (gm < M && gk < K) ? A[(size_t)gm * K + gk] : 0.f;
                }
            }
        }
        #pragma unroll
        for (int it = 0; it < 2; ++it) {
            int fl = tid + it * 256, n = fl >> 2, seg = fl & 3;
            vb[it] = *(const bf16x8*)&Bt[(size_t)(bn + n) * Kp + k0 + seg * 8];
        }
    };
    auto storeTile = [&](int buf) {
        #pragma unroll
        for (int it = 0; it < 4; ++it) {
            int fl = tid + it * 256, row = fl >> 3, kq = fl & 7;
            bf16x4 hi, lo;
            #pragma unroll
            for (int j = 0; j < 4; ++j) {
                hi[j] = (__bf16)va[it][j];
                if (SPLIT) lo[j] = (__bf16)(va[it][j] - (float)hi[j]);
            }
            *(bf16x4*)&sA[buf][row * PAD + kq * 4] = hi;
            if (SPLIT) *(bf16x4*)&sAlo[buf][row * PAD + kq * 4] = lo;
        }
        #pragma unroll
        for (int it = 0; it < 2; ++it) {
            int fl = tid + it * 256, n = fl >> 2, seg = fl & 3;
            *(bf16x8*)&sB[buf][n * PAD + seg * 8] = vb[it];
        }
    };

    int nsteps = (K + 31) / 32;
    loadTile(0);
    storeTile(0);

    for (int s = 0; s < nsteps; ++s) {
        bool more = (s + 1) < nsteps;
        if (more) loadTile((s + 1) * 32);   // in flight across the barrier + MFMAs
        __syncthreads();
        int cur = s & 1;

        bf16x8 af[4], bfr[4], al[4];
        #pragma unroll
        for (int i = 0; i < 4; ++i)
            af[i] = *(bf16x8*)&sA[cur][(wr * 64 + i * 16 + l15) * PAD + quad * 8];
        if (SPLIT) {
            #pragma unroll
            for (int i = 0; i < 4; ++i)
                al[i] = *(bf16x8*)&sAlo[cur][(wr * 64 + i * 16 + l15) * PAD + quad * 8];
        }
        #pragma unroll
        for (int j = 0; j < 4; ++j)
            bfr[j] = *(bf16x8*)&sB[cur][(wc * 64 + j * 16 + l15) * PAD + quad * 8];

        #pragma unroll
        for (int i = 0; i < 4; ++i)
            #pragma unroll
            for (int j = 0; j < 4; ++j) {
                acc[i][j] = __builtin_amdgcn_mfma_f32_16x16x32_bf16(af[i], bfr[j], acc[i][j], 0, 0, 0);
                if (SPLIT)
                    acc[i][j] = __builtin_amdgcn_mfma_f32_16x16x32_bf16(al[i], bfr[j], acc[i][j], 0, 0, 0);
            }
        if (more) storeTile(cur ^ 1);
    }

    // epilogue: C/D layout col=lane&15, row=quad*4+reg
    #pragma unroll
    for (int i = 0; i < 4; ++i) {
        #pragma unroll
        for (int r = 0; r < 4; ++r) {
            int m = bm + wr * 64 + i * 16 + quad * 4 + r;
            if (m < M) {
                #pragma unroll
                for (int j = 0; j < 4; ++j) {
                    int n = bn + wc * 64 + j * 16 + l15;
                    C[(size_t)m * HD + n] = acc[i][j][r];
                }
            }
        }
    }
}

// ---------------- attention logits: att_s/att_d [N,4] ----------------
__global__ __launch_bounds__(256) void att_kernel(const float* __restrict__ hW,
                                                  const float* __restrict__ a_src,
                                                  const float* __restrict__ a_dst,
                                                  float* __restrict__ att_s,
                                                  float* __restrict__ att_d, int N) {
    int n = blockIdx.x;
    int d = threadIdx.x;
    int lane = d & 63, head = d >> 6;
    float h = hW[(size_t)n * HD + d];
    float s = h * a_src[d];
    float t = h * a_dst[d];
    for (int off = 32; off > 0; off >>= 1) {
        s += __shfl_down(s, off, 64);
        t += __shfl_down(t, off, 64);
    }
    if (lane == 0) {
        att_s[n * HEADS + head] = s;
        att_d[n * HEADS + head] = t;
    }
}

// ---------------- GAT edge-softmax + aggregation ----------------
// block = 1 node, 4 waves = 4 heads. Gather: 16 lanes per edge x float4
// (4 edges per wave-instruction, unrolled x2 -> 8 edges in flight).
// NOTE: the 4 sub-groups accumulate DISJOINT edge subsets -> must butterfly-
// reduce across sub (xor 16,32) before writing (R5 bug: missing -> race).
__global__ __launch_bounds__(256) void gat_agg(const float* __restrict__ hW,
                                               const float* __restrict__ att_s,
                                               const float* __restrict__ att_d,
                                               const int* __restrict__ row_ptr,
                                               const int* __restrict__ csr_src,
                                               float* __restrict__ out, int N) {
    int n = blockIdx.x;
    int t = threadIdx.x;
    int lane = t & 63, head = t >> 6;
    int r0 = row_ptr[n], deg = row_ptr[n + 1] - r0;
    float ad = att_d[n * HEADS + head];

    // pass 1: segment max of leaky_relu(att_s[src]+att_d[n])
    float m = -INFINITY;
    for (int base = 0; base < deg; base += 64) {
        int i = base + lane;
        float e = -INFINITY;
        if (i < deg) {
            int s = csr_src[r0 + i];
            float x = att_s[s * HEADS + head] + ad;
            e = (x >= 0.f) ? x : 0.2f * x;
        }
        for (int off = 32; off > 0; off >>= 1) e = fmaxf(e, __shfl_xor(e, off, 64));
        m = fmaxf(m, e);
    }

    // pass 2: weights + vectorized weighted aggregation
    f32x4 acc4 = (f32x4){0.f, 0.f, 0.f, 0.f};
    float wsum = 0.f;
    int sub = lane >> 4;      // edge slot within 4-edge group
    int dq  = lane & 15;      // dim quarter within head
    for (int base = 0; base < deg; base += 64) {
        int i = base + lane;
        float w = 0.f; int s = 0;
        if (i < deg) {
            s = csr_src[r0 + i];
            float x = att_s[s * HEADS + head] + ad;
            x = (x >= 0.f) ? x : 0.2f * x;
            w = expf(x - m);
        }
        wsum += w;
        int cnt = min(64, deg - base);
        for (int j0 = 0; j0 < cnt; j0 += 8) {
            #pragma unroll
            for (int g = 0; g < 2; ++g) {
                int e0 = j0 + g * 4 + sub;
                int ec = min(e0, cnt - 1);
                int   sj = __shfl(s, ec, 64);
                float wj = __shfl(w, ec, 64);
                if (e0 >= cnt) wj = 0.f;
                f32x4 vv = *(const f32x4*)&hW[(size_t)sj * HD + head * DIM + dq * 4];
                #pragma unroll
                for (int c = 0; c < 4; ++c) acc4[c] += wj * vv[c];
            }
        }
    }
    // reduce partial sums across the 4 sub-groups (lanes xor 16, 32)
    #pragma unroll
    for (int c = 0; c < 4; ++c) {
        acc4[c] += __shfl_xor(acc4[c], 16, 64);
        acc4[c] += __shfl_xor(acc4[c], 32, 64);
    }
    for (int off = 32; off > 0; off >>= 1) wsum += __shfl_xor(wsum, off, 64);
    if (sub == 0) {
        float inv = 1.f / (wsum + 1e-9f);
        f32x4 o;
        #pragma unroll
        for (int c = 0; c < 4; ++c) {
            float v = acc4[c] * inv;
            o[c] = (v > 0.f) ? v : expm1f(v);  // ELU
        }
        *(f32x4*)&out[(size_t)n * HD + head * DIM + dq * 4] = o;
    }
}

// ---------------- mean pool per graph + final linear (f32 output) ----------------
__global__ __launch_bounds__(256) void pool_out(const float* __restrict__ h,
                                                const int* __restrict__ gid,
                                                const float* __restrict__ W_out,
                                                const float* __restrict__ b_out,
                                                const float* __restrict__ scores,
                                                float* __restrict__ out, int N) {
    int b = blockIdx.x;
    int j = threadIdx.x;
    int l = 0, r = N;
    while (l < r) { int mid = (l + r) >> 1; if (gid[mid] < b) l = mid + 1; else r = mid; }
    int lo = l;
    r = N;
    while (l < r) { int mid = (l + r) >> 1; if (gid[mid] < b + 1) l = mid + 1; else r = mid; }
    int hi = l;

    float sum = 0.f;
    for (int n = lo; n < hi; ++n) sum += h[(size_t)n * HD + j];
    int cnt = hi - lo;
    float pooled = sum / fmaxf((float)cnt, 1.f);
    float val = pooled * W_out[j];

    __shared__ float red[256];
    red[j] = val;
    __syncthreads();
    for (int s = 128; s > 0; s >>= 1) {
        if (j < s) red[j] += red[j + s];
        __syncthreads();
    }
    if (j == 0) {
        out[b] = red[0] + scores[b] * W_out[HD] + b_out[0];
    }
}

// ---------------- host ----------------

static inline size_t al256(size_t x) { return (x + 255) & ~(size_t)255; }

#define KP_LIG  96
#define KP_PROT 1280
#define KP_HID  256

extern "C" void kernel_launch(void* const* d_in, const int* in_sizes, int n_in,
                              void* d_out, int out_size, void* d_ws, size_t ws_size,
                              hipStream_t stream) {
    const float* ligand_x  = (const float*)d_in[0];
    const float* protein_x = (const float*)d_in[1];
    const float* W_lig     = (const float*)d_in[2];
    const float* W_prot    = (const float*)d_in[3];
    const float* W1        = (const float*)d_in[4];
    const float* a1_src    = (const float*)d_in[5];
    const float* a1_dst    = (const float*)d_in[6];
    const float* W2        = (const float*)d_in[7];
    const float* a2_src    = (const float*)d_in[8];
    const float* a2_dst    = (const float*)d_in[9];
    const float* W_out     = (const float*)d_in[10];
    const float* b_out     = (const float*)d_in[11];
    const int*   edge_src  = (const int*)d_in[12];
    const int*   edge_dst  = (const int*)d_in[13];
    const int*   graph_ids = (const int*)d_in[14];
    const float* scores    = (const float*)d_in[15];
    float* out = (float*)d_out;

    // workspace layout
    char* w = (char*)d_ws;
    float* xbuf = (float*)w;            w += al256((size_t)NN * HD * 4);
    float* hbuf = (float*)w;            w += al256((size_t)NN * HD * 4);
    float* atts = (float*)w;            w += al256((size_t)NN * HEADS * 4);
    float* attd = (float*)w;            w += al256((size_t)NN * HEADS * 4);
    int* counts  = (int*)w;             w += al256((size_t)NN * 4);
    int* incl    = (int*)w;             w += al256((size_t)NN * 4);
    int* bsum    = (int*)w;             w += al256(64 * 4);
    int* row_ptr = (int*)w;             w += al256((size_t)(NN + 1) * 4);
    int* cursor  = (int*)w;             w += al256((size_t)NN * 4);
    int* csr_src = (int*)w;             w += al256((size_t)EDGES * 4);
    __bf16* Bt_lig  = (__bf16*)w;       w += al256((size_t)HD * KP_LIG * 2);
    __bf16* Bt_prot = (__bf16*)w;       w += al256((size_t)HD * KP_PROT * 2);
    __bf16* Bt_W1   = (__bf16*)w;       w += al256((size_t)HD * KP_HID * 2);
    __bf16* Bt_W2   = (__bf16*)w;       w += al256((size_t)HD * KP_HID * 2);

    const int NB_SCAN = (NN + 1023) / 1024;  // 49

    hipMemsetAsync(counts, 0, (size_t)NN * 4, stream);
    hipMemsetAsync(cursor, 0, (size_t)NN * 4, stream);

    // --- weight convert/transpose to bf16 (exact: inputs are bf16-rounded) ---
    k_wcvt<<<HD, 256, 0, stream>>>(W_lig,  Bt_lig,  F_LIG,  KP_LIG);
    k_wcvt<<<HD, 256, 0, stream>>>(W_prot, Bt_prot, F_PROT, KP_PROT);
    k_wcvt<<<HD, 256, 0, stream>>>(W1,     Bt_W1,   HD,     KP_HID);
    k_wcvt<<<HD, 256, 0, stream>>>(W2,     Bt_W2,   HD,     KP_HID);

    // --- CSR by destination ---
    k_hist<<<(EDGES + 255) / 256, 256, 0, stream>>>(edge_dst, counts, EDGES);
    k_scan1<<<NB_SCAN, 1024, 0, stream>>>(counts, incl, bsum, NN);
    k_scan2<<<1, 1, 0, stream>>>(bsum, NB_SCAN, row_ptr, NN, EDGES);
    k_scan3<<<NB_SCAN, 1024, 0, stream>>>(incl, counts, bsum, row_ptr, NN);
    k_scatter<<<(EDGES + 255) / 256, 256, 0, stream>>>(edge_src, edge_dst, row_ptr,
                                                       cursor, csr_src, EDGES);

    // --- input projections -> xbuf [NN,256] (A is bf16-exact: SPLIT=0) ---
    mfma_gemm<0><<<dim3(2, (N_LIG + 127) / 128), 256, 0, stream>>>(
        ligand_x, Bt_lig, xbuf, N_LIG, F_LIG, KP_LIG);
    mfma_gemm<0><<<dim3(2, (N_PROT + 127) / 128), 256, 0, stream>>>(
        protein_x, Bt_prot, xbuf + (size_t)N_LIG * HD, N_PROT, F_PROT, KP_PROT);

    // --- GAT layer 1 ---
    mfma_gemm<1><<<dim3(2, (NN + 127) / 128), 256, 0, stream>>>(
        xbuf, Bt_W1, hbuf, NN, HD, KP_HID);
    att_kernel<<<NN, 256, 0, stream>>>(hbuf, a1_src, a1_dst, atts, attd, NN);
    gat_agg<<<NN, 256, 0, stream>>>(hbuf, atts, attd, row_ptr, csr_src, xbuf, NN);

    // --- GAT layer 2 ---
    mfma_gemm<1><<<dim3(2, (NN + 127) / 128), 256, 0, stream>>>(
        xbuf, Bt_W2, hbuf, NN, HD, KP_HID);
    att_kernel<<<NN, 256, 0, stream>>>(hbuf, a2_src, a2_dst, atts, attd, NN);
    gat_agg<<<NN, 256, 0, stream>>>(hbuf, atts, attd, row_ptr, csr_src, xbuf, NN);

    // --- pool + final linear ---
    pool_out<<<BATCH, 256, 0, stream>>>(xbuf, graph_ids, W_out, b_out, scores, out, NN);
}

// Round 7
// 745.551 us; speedup vs baseline: 2.3470x; 1.1106x over previous
//
#include <hip/hip_runtime.h>
#include <hip/hip_bf16.h>

// Problem dims (fixed)
#define N_LIG   10000
#define N_PROT  40000
#define NN      50000     // total nodes
#define EDGES   400000
#define BATCH   512
#define F_LIG   74
#define F_PROT  1280
#define HD      256       // H*D
#define HEADS   4
#define DIM     64

typedef __bf16 bf16x8 __attribute__((ext_vector_type(8)));
typedef __bf16 bf16x4 __attribute__((ext_vector_type(4)));
typedef float  f32x4  __attribute__((ext_vector_type(4)));

// ---------------- CSR build ----------------

__global__ void k_hist(const int* __restrict__ dst, int* __restrict__ counts, int E) {
    int e = blockIdx.x * blockDim.x + threadIdx.x;
    if (e < E) atomicAdd(&counts[dst[e]], 1);
}

__global__ __launch_bounds__(1024) void k_scan1(const int* __restrict__ counts,
                                                int* __restrict__ incl,
                                                int* __restrict__ bsum, int N) {
    __shared__ int tmp[1024];
    int i = blockIdx.x * 1024 + threadIdx.x;
    int v = (i < N) ? counts[i] : 0;
    tmp[threadIdx.x] = v;
    __syncthreads();
    for (int off = 1; off < 1024; off <<= 1) {
        int add = (threadIdx.x >= (unsigned)off) ? tmp[threadIdx.x - off] : 0;
        __syncthreads();
        tmp[threadIdx.x] += add;
        __syncthreads();
    }
    if (i < N) incl[i] = tmp[threadIdx.x];
    if (threadIdx.x == 1023) bsum[blockIdx.x] = tmp[1023];
}

__global__ void k_scan2(int* __restrict__ bsum, int nb, int* __restrict__ row_ptr, int N, int E) {
    if (threadIdx.x == 0 && blockIdx.x == 0) {
        int run = 0;
        for (int i = 0; i < nb; ++i) { int v = bsum[i]; bsum[i] = run; run += v; }
        row_ptr[N] = E;
    }
}

__global__ __launch_bounds__(1024) void k_scan3(const int* __restrict__ incl,
                                                const int* __restrict__ counts,
                                                const int* __restrict__ bsum,
                                                int* __restrict__ row_ptr, int N) {
    int i = blockIdx.x * 1024 + threadIdx.x;
    if (i < N) row_ptr[i] = bsum[blockIdx.x] + incl[i] - counts[i];  // exclusive
}

__global__ void k_scatter(const int* __restrict__ src, const int* __restrict__ dst,
                          const int* __restrict__ row_ptr, int* __restrict__ cursor,
                          int* __restrict__ csr_src, int E) {
    int e = blockIdx.x * blockDim.x + threadIdx.x;
    if (e < E) {
        int d = dst[e];
        int pos = row_ptr[d] + atomicAdd(&cursor[d], 1);
        csr_src[pos] = src[e];
    }
}

// ---------------- weight transpose+convert: W f32 [K,256] -> Bt bf16 [256][Kp] ----------------
__global__ __launch_bounds__(256) void k_wcvt(const float* __restrict__ W,
                                              __bf16* __restrict__ Bt, int K, int Kp) {
    int n = blockIdx.x;   // 0..255
    for (int k = threadIdx.x; k < Kp; k += blockDim.x)
        Bt[(size_t)n * Kp + k] = (k < K) ? (__bf16)W[(size_t)k * HD + n] : (__bf16)0.f;
}

// ---------------- MFMA GEMM, 64x128 tile, double-buffered ----------------
// MODE=0 (proj): A bf16-exact f32 -> C f32. LDS: sA bf16-hi 2buf + sB. 5 blk/CU.
// MODE=1 (layer): A f32 (hi/lo at frag-load) -> Hbf bf16 + fused att logits.
//                 LDS: sA f32 2buf + sB. 4 blk/CU.
// 4 waves in 2x2 (wave = 32 rows x 64 cols = one head's dims), 2x4 frags/wave.
template <int MODE>
__global__ __launch_bounds__(256, MODE ? 4 : 5)
void mfma_gemm(const float* __restrict__ A, const __bf16* __restrict__ Bt,
               float* __restrict__ C,
               __bf16* __restrict__ Hbf, float* __restrict__ atts, float* __restrict__ attd,
               const float* __restrict__ a_src, const float* __restrict__ a_dst,
               int M, int K, int Kp) {
    // manual LDS layout (avoid undead arrays: R6 showed unused __shared__ not DCE'd)
    // MODE0: sAh 2*64*40 bf16 = 10240B | sB 2*128*40 bf16 = 20480B  -> 30720
    // MODE1: sAf 2*64*36 f32  = 18432B | sB                          -> 38912
    __shared__ __align__(16) unsigned char smem[MODE ? (18432 + 20480) : (10240 + 20480)];
    __bf16* sAh = (__bf16*)smem;
    float*  sAf = (float*)smem;
    __bf16* sB  = (__bf16*)(smem + (MODE ? 18432 : 10240));

    int tid  = threadIdx.x;
    int bm   = blockIdx.y * 64;
    int bn   = blockIdx.x * 128;
    int lane = tid & 63, wave = tid >> 6;
    int wr   = wave >> 1, wc = wave & 1;
    int l15  = lane & 15, quad = lane >> 4;

    f32x4 acc[2][4];
    #pragma unroll
    for (int i = 0; i < 2; ++i)
        #pragma unroll
        for (int j = 0; j < 4; ++j)
            acc[i][j] = (f32x4){0.f, 0.f, 0.f, 0.f};

    const bool k4 = (K & 3) == 0;
    float  va[2][4];
    bf16x8 vb[2];

    auto loadTile = [&](int k0) {
        bool fullk = k4 && (k0 + 32 <= K);
        #pragma unroll
        for (int it = 0; it < 2; ++it) {
            int fl = tid + it * 256, row = fl >> 3, kq = fl & 7;   // rows 0..63
            int gm = bm + row;
            if (gm < M && fullk) {
                f32x4 t = *(const f32x4*)&A[(size_t)gm * K + k0 + kq * 4];
                va[it][0] = t[0]; va[it][1] = t[1]; va[it][2] = t[2]; va[it][3] = t[3];
            } else {
                #pragma unroll
                for (int j = 0; j < 4; ++j) {
                    int gk = k0 + kq * 4 + j;
                    va[it][j] = (gm < M && gk < K) ? A[(size_t)gm * K + gk] : 0.f;
                }
            }
        }
        #pragma unroll
        for (int it = 0; it < 2; ++it) {
            int fl = tid + it * 256, n = fl >> 2, seg = fl & 3;    // n 0..127
            vb[it] = *(const bf16x8*)&Bt[(size_t)(bn + n) * Kp + k0 + seg * 8];
        }
    };
    auto storeTile = [&](int buf) {
        #pragma unroll
        for (int it = 0; it < 2; ++it) {
            int fl = tid + it * 256, row = fl >> 3, kq = fl & 7;
            if (MODE == 0) {
                bf16x4 hi;
                #pragma unroll
                for (int j = 0; j < 4; ++j) hi[j] = (__bf16)va[it][j];
                *(bf16x4*)&sAh[buf * 2560 + row * 40 + kq * 4] = hi;
            } else {
                f32x4 t = {va[it][0], va[it][1], va[it][2], va[it][3]};
                *(f32x4*)&sAf[buf * 2304 + row * 36 + kq * 4] = t;
            }
        }
        #pragma unroll
        for (int it = 0; it < 2; ++it) {
            int fl = tid + it * 256, n = fl >> 2, seg = fl & 3;
            *(bf16x8*)&sB[buf * 5120 + n * 40 + seg * 8] = vb[it];
        }
    };

    int nsteps = (K + 31) / 32;
    loadTile(0);
    storeTile(0);

    for (int s = 0; s < nsteps; ++s) {
        bool more = (s + 1) < nsteps;
        if (more) loadTile((s + 1) * 32);
        __syncthreads();
        int cur = s & 1;

        bf16x8 af[2], al[2], bfr[4];
        #pragma unroll
        for (int i = 0; i < 2; ++i) {
            if (MODE == 0) {
                af[i] = *(bf16x8*)&sAh[cur * 2560 + (wr * 32 + i * 16 + l15) * 40 + quad * 8];
            } else {
                int base = cur * 2304 + (wr * 32 + i * 16 + l15) * 36 + quad * 8;
                f32x4 p0 = *(f32x4*)&sAf[base];
                f32x4 p1 = *(f32x4*)&sAf[base + 4];
                #pragma unroll
                for (int c = 0; c < 8; ++c) {
                    float x = (c < 4) ? p0[c] : p1[c - 4];
                    __bf16 h = (__bf16)x;
                    af[i][c] = h;
                    al[i][c] = (__bf16)(x - (float)h);
                }
            }
        }
        #pragma unroll
        for (int j = 0; j < 4; ++j)
            bfr[j] = *(bf16x8*)&sB[cur * 5120 + (wc * 64 + j * 16 + l15) * 40 + quad * 8];

        #pragma unroll
        for (int i = 0; i < 2; ++i)
            #pragma unroll
            for (int j = 0; j < 4; ++j) {
                acc[i][j] = __builtin_amdgcn_mfma_f32_16x16x32_bf16(af[i], bfr[j], acc[i][j], 0, 0, 0);
                if (MODE)
                    acc[i][j] = __builtin_amdgcn_mfma_f32_16x16x32_bf16(al[i], bfr[j], acc[i][j], 0, 0, 0);
            }
        if (more) storeTile(cur ^ 1);
    }

    // ---- epilogue: C/D layout col=lane&15, row=quad*4+reg ----
    if (MODE == 0) {
        #pragma unroll
        for (int i = 0; i < 2; ++i)
            #pragma unroll
            for (int r = 0; r < 4; ++r) {
                int m = bm + wr * 32 + i * 16 + quad * 4 + r;
                if (m < M) {
                    #pragma unroll
                    for (int j = 0; j < 4; ++j)
                        C[(size_t)m * HD + bn + wc * 64 + j * 16 + l15] = acc[i][j][r];
                }
            }
    } else {
        int head = (bn >> 6) + wc;           // this wave's 64 cols == one head
        float as[4], ad2[4];
        #pragma unroll
        for (int j = 0; j < 4; ++j) {
            as[j]  = a_src[head * DIM + j * 16 + l15];
            ad2[j] = a_dst[head * DIM + j * 16 + l15];
        }
        #pragma unroll
        for (int i = 0; i < 2; ++i)
            #pragma unroll
            for (int r = 0; r < 4; ++r) {
                int m = bm + wr * 32 + i * 16 + quad * 4 + r;
                bool ok = m < M;
                float s = 0.f, t = 0.f;
                #pragma unroll
                for (int j = 0; j < 4; ++j) {
                    float v = acc[i][j][r];
                    if (ok) Hbf[(size_t)m * HD + head * DIM + j * 16 + l15] = (__bf16)v;
                    s += v * as[j];
                    t += v * ad2[j];
                }
                #pragma unroll
                for (int mask = 1; mask <= 8; mask <<= 1) {
                    s += __shfl_xor(s, mask, 64);
                    t += __shfl_xor(t, mask, 64);
                }
                if (ok && l15 == 0) {
                    atts[m * HEADS + head] = s;
                    attd[m * HEADS + head] = t;
                }
            }
    }
}

// ---------------- GAT edge-softmax + aggregation (bf16 gather) ----------------
// block = 1 node, 4 waves = 4 heads. Gather: 16 lanes/edge x bf16x4 (8B)
// -> 4 edges per wave-instruction, unrolled x2. Butterfly-reduce across the
// 4 edge-subgroups (xor 16,32) before the single write (R5 lesson).
__global__ __launch_bounds__(256) void gat_agg(const __bf16* __restrict__ hW,
                                               const float* __restrict__ att_s,
                                               const float* __restrict__ att_d,
                                               const int* __restrict__ row_ptr,
                                               const int* __restrict__ csr_src,
                                               float* __restrict__ out, int N) {
    int n = blockIdx.x;
    int t = threadIdx.x;
    int lane = t & 63, head = t >> 6;
    int r0 = row_ptr[n], deg = row_ptr[n + 1] - r0;
    float ad = att_d[n * HEADS + head];

    // pass 1: segment max of leaky_relu(att_s[src]+att_d[n])
    float m = -INFINITY;
    for (int base = 0; base < deg; base += 64) {
        int i = base + lane;
        float e = -INFINITY;
        if (i < deg) {
            int s = csr_src[r0 + i];
            float x = att_s[s * HEADS + head] + ad;
            e = (x >= 0.f) ? x : 0.2f * x;
        }
        for (int off = 32; off > 0; off >>= 1) e = fmaxf(e, __shfl_xor(e, off, 64));
        m = fmaxf(m, e);
    }

    // pass 2: weights + vectorized weighted aggregation (bf16 h)
    f32x4 acc4 = (f32x4){0.f, 0.f, 0.f, 0.f};
    float wsum = 0.f;
    int sub = lane >> 4;      // edge slot within 4-edge group
    int dq  = lane & 15;      // dim quarter within head
    for (int base = 0; base < deg; base += 64) {
        int i = base + lane;
        float w = 0.f; int s = 0;
        if (i < deg) {
            s = csr_src[r0 + i];
            float x = att_s[s * HEADS + head] + ad;
            x = (x >= 0.f) ? x : 0.2f * x;
            w = expf(x - m);
        }
        wsum += w;
        int cnt = min(64, deg - base);
        for (int j0 = 0; j0 < cnt; j0 += 8) {
            #pragma unroll
            for (int g = 0; g < 2; ++g) {
                int e0 = j0 + g * 4 + sub;
                int ec = min(e0, cnt - 1);
                int   sj = __shfl(s, ec, 64);
                float wj = __shfl(w, ec, 64);
                if (e0 >= cnt) wj = 0.f;
                bf16x4 v4 = *(const bf16x4*)&hW[(size_t)sj * HD + head * DIM + dq * 4];
                #pragma unroll
                for (int c = 0; c < 4; ++c) acc4[c] += wj * (float)v4[c];
            }
        }
    }
    #pragma unroll
    for (int c = 0; c < 4; ++c) {
        acc4[c] += __shfl_xor(acc4[c], 16, 64);
        acc4[c] += __shfl_xor(acc4[c], 32, 64);
    }
    for (int off = 32; off > 0; off >>= 1) wsum += __shfl_xor(wsum, off, 64);
    if (sub == 0) {
        float inv = 1.f / (wsum + 1e-9f);
        f32x4 o;
        #pragma unroll
        for (int c = 0; c < 4; ++c) {
            float v = acc4[c] * inv;
            o[c] = (v > 0.f) ? v : expm1f(v);  // ELU
        }
        *(f32x4*)&out[(size_t)n * HD + head * DIM + dq * 4] = o;
    }
}

// ---------------- mean pool per graph + final linear (f32 output) ----------------
__global__ __launch_bounds__(256) void pool_out(const float* __restrict__ h,
                                                const int* __restrict__ gid,
                                                const float* __restrict__ W_out,
                                                const float* __restrict__ b_out,
                                                const float* __restrict__ scores,
                                                float* __restrict__ out, int N) {
    int b = blockIdx.x;
    int j = threadIdx.x;
    int l = 0, r = N;
    while (l < r) { int mid = (l + r) >> 1; if (gid[mid] < b) l = mid + 1; else r = mid; }
    int lo = l;
    r = N;
    while (l < r) { int mid = (l + r) >> 1; if (gid[mid] < b + 1) l = mid + 1; else r = mid; }
    int hi = l;

    float sum = 0.f;
    for (int n = lo; n < hi; ++n) sum += h[(size_t)n * HD + j];
    int cnt = hi - lo;
    float pooled = sum / fmaxf((float)cnt, 1.f);
    float val = pooled * W_out[j];

    __shared__ float red[256];
    red[j] = val;
    __syncthreads();
    for (int s = 128; s > 0; s >>= 1) {
        if (j < s) red[j] += red[j + s];
        __syncthreads();
    }
    if (j == 0) {
        out[b] = red[0] + scores[b] * W_out[HD] + b_out[0];
    }
}

// ---------------- host ----------------

static inline size_t al256(size_t x) { return (x + 255) & ~(size_t)255; }

#define KP_LIG  96
#define KP_PROT 1280
#define KP_HID  256

extern "C" void kernel_launch(void* const* d_in, const int* in_sizes, int n_in,
                              void* d_out, int out_size, void* d_ws, size_t ws_size,
                              hipStream_t stream) {
    const float* ligand_x  = (const float*)d_in[0];
    const float* protein_x = (const float*)d_in[1];
    const float* W_lig     = (const float*)d_in[2];
    const float* W_prot    = (const float*)d_in[3];
    const float* W1        = (const float*)d_in[4];
    const float* a1_src    = (const float*)d_in[5];
    const float* a1_dst    = (const float*)d_in[6];
    const float* W2        = (const float*)d_in[7];
    const float* a2_src    = (const float*)d_in[8];
    const float* a2_dst    = (const float*)d_in[9];
    const float* W_out     = (const float*)d_in[10];
    const float* b_out     = (const float*)d_in[11];
    const int*   edge_src  = (const int*)d_in[12];
    const int*   edge_dst  = (const int*)d_in[13];
    const int*   graph_ids = (const int*)d_in[14];
    const float* scores    = (const float*)d_in[15];
    float* out = (float*)d_out;

    // workspace layout
    char* w = (char*)d_ws;
    float*  xbuf = (float*)w;           w += al256((size_t)NN * HD * 4);
    __bf16* Hbf  = (__bf16*)w;          w += al256((size_t)NN * HD * 2);
    float* atts = (float*)w;            w += al256((size_t)NN * HEADS * 4);
    float* attd = (float*)w;            w += al256((size_t)NN * HEADS * 4);
    int* counts  = (int*)w;             w += al256((size_t)NN * 4);
    int* incl    = (int*)w;             w += al256((size_t)NN * 4);
    int* bsum    = (int*)w;             w += al256(64 * 4);
    int* row_ptr = (int*)w;             w += al256((size_t)(NN + 1) * 4);
    int* cursor  = (int*)w;             w += al256((size_t)NN * 4);
    int* csr_src = (int*)w;             w += al256((size_t)EDGES * 4);
    __bf16* Bt_lig  = (__bf16*)w;       w += al256((size_t)HD * KP_LIG * 2);
    __bf16* Bt_prot = (__bf16*)w;       w += al256((size_t)HD * KP_PROT * 2);
    __bf16* Bt_W1   = (__bf16*)w;       w += al256((size_t)HD * KP_HID * 2);
    __bf16* Bt_W2   = (__bf16*)w;       w += al256((size_t)HD * KP_HID * 2);

    const int NB_SCAN = (NN + 1023) / 1024;  // 49

    hipMemsetAsync(counts, 0, (size_t)NN * 4, stream);
    hipMemsetAsync(cursor, 0, (size_t)NN * 4, stream);

    // --- weight convert/transpose to bf16 (exact: inputs are bf16-rounded) ---
    k_wcvt<<<HD, 256, 0, stream>>>(W_lig,  Bt_lig,  F_LIG,  KP_LIG);
    k_wcvt<<<HD, 256, 0, stream>>>(W_prot, Bt_prot, F_PROT, KP_PROT);
    k_wcvt<<<HD, 256, 0, stream>>>(W1,     Bt_W1,   HD,     KP_HID);
    k_wcvt<<<HD, 256, 0, stream>>>(W2,     Bt_W2,   HD,     KP_HID);

    // --- CSR by destination ---
    k_hist<<<(EDGES + 255) / 256, 256, 0, stream>>>(edge_dst, counts, EDGES);
    k_scan1<<<NB_SCAN, 1024, 0, stream>>>(counts, incl, bsum, NN);
    k_scan2<<<1, 1, 0, stream>>>(bsum, NB_SCAN, row_ptr, NN, EDGES);
    k_scan3<<<NB_SCAN, 1024, 0, stream>>>(incl, counts, bsum, row_ptr, NN);
    k_scatter<<<(EDGES + 255) / 256, 256, 0, stream>>>(edge_src, edge_dst, row_ptr,
                                                       cursor, csr_src, EDGES);

    // --- input projections -> xbuf [NN,256] (A bf16-exact: MODE=0) ---
    mfma_gemm<0><<<dim3(2, (N_LIG + 63) / 64), 256, 0, stream>>>(
        ligand_x, Bt_lig, xbuf, nullptr, nullptr, nullptr, nullptr, nullptr,
        N_LIG, F_LIG, KP_LIG);
    mfma_gemm<0><<<dim3(2, (N_PROT + 63) / 64), 256, 0, stream>>>(
        protein_x, Bt_prot, xbuf + (size_t)N_LIG * HD, nullptr, nullptr, nullptr,
        nullptr, nullptr, N_PROT, F_PROT, KP_PROT);

    // --- GAT layer 1: GEMM (+fused att, bf16 h) -> gather ---
    mfma_gemm<1><<<dim3(2, (NN + 63) / 64), 256, 0, stream>>>(
        xbuf, Bt_W1, nullptr, Hbf, atts, attd, a1_src, a1_dst, NN, HD, KP_HID);
    gat_agg<<<NN, 256, 0, stream>>>(Hbf, atts, attd, row_ptr, csr_src, xbuf, NN);

    // --- GAT layer 2 ---
    mfma_gemm<1><<<dim3(2, (NN + 63) / 64), 256, 0, stream>>>(
        xbuf, Bt_W2, nullptr, Hbf, atts, attd, a2_src, a2_dst, NN, HD, KP_HID);
    gat_agg<<<NN, 256, 0, stream>>>(Hbf, atts, attd, row_ptr, csr_src, xbuf, NN);

    // --- pool + final linear ---
    pool_out<<<BATCH, 256, 0, stream>>>(xbuf, graph_ids, W_out, b_out, scores, out, NN);
}